// Round 1
// baseline (381.207 us; speedup 1.0000x reference)
//
#include <hip/hip_runtime.h>

typedef _Float16 half_t;
typedef _Float16 half8 __attribute__((ext_vector_type(8)));
typedef float f32x4 __attribute__((ext_vector_type(4)));

#define D_EMBED   1024
#define D_CROSS   768
#define N_HEADS   8
#define D_HEAD    128
#define BATCH     8
#define SEQ_Q     4096
#define SEQ_KV    77
#define M_Q       (BATCH*SEQ_Q)     /* 32768 */
#define ROWS_KV   (BATCH*SEQ_KV)    /* 616   */
#define ROWS_KV_PAD 640

// ---------------- workspace layout (bytes, all 256-aligned) ----------------
#define WS_Q     ((size_t)0)                                  // q, later attn-out in place: 32768*1024*2
#define WS_WQT   (WS_Q    + (size_t)M_Q*D_EMBED*2)            // Wq^T fp16 [1024][1024]
#define WS_WOT   (WS_WQT  + (size_t)D_EMBED*D_EMBED*2)        // Wo^T fp16 [1024][1024]
#define WS_WKVT  (WS_WOT  + (size_t)D_EMBED*D_EMBED*2)        // [Wk;Wv]^T fp16 [2048][768]
#define WS_YH    (WS_WKVT + (size_t)2*D_EMBED*D_CROSS*2)      // y fp16 padded [640][768]
#define WS_KV    (WS_YH   + (size_t)ROWS_KV_PAD*D_CROSS*2)    // kv fp16 [640][2048]
#define WS_BKV   (WS_KV   + (size_t)ROWS_KV_PAD*2*D_EMBED*2)  // bias concat fp32 [2048]

__device__ __forceinline__ void gload_lds16(const void* g, void* lds) {
  __builtin_amdgcn_global_load_lds(
      (const __attribute__((address_space(1))) unsigned int*)g,
      (__attribute__((address_space(3))) unsigned int*)lds, 16, 0, 0);
}

// ---------------- prep kernels ----------------
// dst[n][k] = (half) src[k][n];   src is [K][N] fp32, dst is [N][K] fp16
__global__ void transpose_f32f16(const float* __restrict__ src, half_t* __restrict__ dst,
                                 int K, int N) {
  __shared__ float tile[32][33];
  int n0 = blockIdx.x * 32, k0 = blockIdx.y * 32;
  int tx = threadIdx.x, ty = threadIdx.y;
#pragma unroll
  for (int j = 0; j < 4; ++j)
    tile[ty + j*8][tx] = src[(size_t)(k0 + ty + j*8)*N + n0 + tx];
  __syncthreads();
#pragma unroll
  for (int j = 0; j < 4; ++j)
    dst[(size_t)(n0 + ty + j*8)*K + k0 + tx] = (half_t)tile[tx][ty + j*8];
}

__global__ void convert_pad_y(const float* __restrict__ y, half_t* __restrict__ yh) {
  int idx = blockIdx.x * 256 + threadIdx.x;         // grid covers 640*768 exactly
  int s = idx / D_CROSS;
  yh[idx] = (s < ROWS_KV) ? (half_t)y[idx] : (half_t)0.f;
}

__global__ void concat_bias(const float* __restrict__ bk, const float* __restrict__ bv,
                            float* __restrict__ bkv) {
  int i = blockIdx.x * 256 + threadIdx.x;           // grid = 2048 threads
  bkv[i] = (i < D_EMBED) ? bk[i] : bv[i - D_EMBED];
}

// ---------------- GEMM: C[M,N] = A[M,K] * Bt[N,K]^T + bias[N] ----------------
// 128x128 tile, BK=32, 256 threads (4 waves), wave tile 64x64 = 4x4 frags of 16x16x32_f16.
// AF32: A is fp32 in global, reg-stage + convert to fp16 LDS. Else fp16 via global_load_lds.
template<bool AF32, bool OUTF32>
__global__ __launch_bounds__(256, 2)
void gemm_f16(const void* __restrict__ Av, const half_t* __restrict__ Bt,
              const float* __restrict__ bias, void* __restrict__ Cv,
              int M, int N, int K) {
  __shared__ half_t As[128*32];
  __shared__ half_t Bs[128*32];
  const int tid = threadIdx.x;
  const int l  = tid & 63;
  const int w  = tid >> 6;
  const int l4 = l & 15, lh = l >> 4;
  const int bn0 = blockIdx.x * 128;
  const int bm0 = blockIdx.y * 128;
  const int wr = w >> 1, wc = w & 1;

  f32x4 acc[4][4] = {};
  const int nk = K >> 5;

  for (int kt = 0; kt < nk; ++kt) {
    // ---- stage B (always fp16, global_load_lds 16B) : Bs[row_n][k] ----
    {
      const half_t* g0 = Bt + (size_t)(bn0 + w*16 + (l >> 2))*K + kt*32 + (l & 3)*8;
      gload_lds16(g0, (char*)Bs + w*1024);
      const half_t* g1 = Bt + (size_t)(bn0 + 64 + w*16 + (l >> 2))*K + kt*32 + (l & 3)*8;
      gload_lds16(g1, (char*)Bs + 4096 + w*1024);
    }
    // ---- stage A ----
    if constexpr (!AF32) {
      const half_t* A = (const half_t*)Av;
      const half_t* g0 = A + (size_t)(bm0 + w*16 + (l >> 2))*K + kt*32 + (l & 3)*8;
      gload_lds16(g0, (char*)As + w*1024);
      const half_t* g1 = A + (size_t)(bm0 + 64 + w*16 + (l >> 2))*K + kt*32 + (l & 3)*8;
      gload_lds16(g1, (char*)As + 4096 + w*1024);
    } else {
      const float* A = (const float*)Av;
      const int row = tid >> 2;            // 0..63
      const int c0  = (tid & 3) * 8;       // half-elem col
#pragma unroll
      for (int r = 0; r < 2; ++r) {
        const float* g = A + (size_t)(bm0 + r*64 + row)*K + kt*32 + c0;
        f32x4 f0 = *(const f32x4*)g;
        f32x4 f1 = *(const f32x4*)(g + 4);
        half8 hv;
        hv[0]=(half_t)f0[0]; hv[1]=(half_t)f0[1]; hv[2]=(half_t)f0[2]; hv[3]=(half_t)f0[3];
        hv[4]=(half_t)f1[0]; hv[5]=(half_t)f1[1]; hv[6]=(half_t)f1[2]; hv[7]=(half_t)f1[3];
        *(half8*)(As + (size_t)(r*64 + row)*32 + c0) = hv;
      }
    }
    __syncthreads();
    // ---- compute ----
    half8 af[4], bf[4];
#pragma unroll
    for (int m = 0; m < 4; ++m)
      af[m] = *(const half8*)(As + (size_t)(wr*64 + m*16 + l4)*32 + lh*8);
#pragma unroll
    for (int n = 0; n < 4; ++n)
      bf[n] = *(const half8*)(Bs + (size_t)(wc*64 + n*16 + l4)*32 + lh*8);
#pragma unroll
    for (int m = 0; m < 4; ++m)
#pragma unroll
      for (int n = 0; n < 4; ++n)
        acc[m][n] = __builtin_amdgcn_mfma_f32_16x16x32_f16(af[m], bf[n], acc[m][n], 0, 0, 0);
    __syncthreads();
  }

  // ---- epilogue: C row = bm0+wr*64+m*16+lh*4+j, col = bn0+wc*64+n*16+l4 ----
  const int c_base = bn0 + wc*64;
  const int r_base = bm0 + wr*64;
#pragma unroll
  for (int n = 0; n < 4; ++n) {
    const int col = c_base + n*16 + l4;
    const float bvv = bias[col];
#pragma unroll
    for (int m = 0; m < 4; ++m) {
#pragma unroll
      for (int j = 0; j < 4; ++j) {
        const int row = r_base + m*16 + lh*4 + j;
        const float v = acc[m][n][j] + bvv;
        if constexpr (OUTF32) ((float*)Cv)[(size_t)row*N + col] = v;
        else                  ((half_t*)Cv)[(size_t)row*N + col] = (half_t)v;
      }
    }
  }
}

// ---------------- attention ----------------
// grid (64 q-tiles, 64 bh). Block = 4 waves, each wave = 16 q rows.
// q: [32768][1024] fp16 (in-place output). kv: [640][2048] fp16, k cols 0..1023, v cols 1024..2047.
__global__ __launch_bounds__(256, 2)
void attn_kernel(half_t* __restrict__ q, const half_t* __restrict__ kv) {
  __shared__ half_t K_lds[80*136];     // [kv_row][d], stride 136 halfs (272B, 16B-mult)
  __shared__ half_t Vt_lds[128*104];   // [d][kv_row], stride 104 halfs (208B, 16B-mult)
  __shared__ half_t P_lds[64*104];     // [q_row 0..63][kv 0..95 + pad]
  const int tid = threadIdx.x;
  const int l = tid & 63, w = tid >> 6;
  const int l4 = l & 15, lh = l >> 4;
  const int bh = blockIdx.y;
  const int b = bh >> 3, h = bh & 7;
  const size_t kvbase = (size_t)b*SEQ_KV*2048 + (size_t)h*D_HEAD;

  // stage K: 80 rows x 128 d (zero-pad rows >= 77)
  for (int i = tid; i < 80*16; i += 256) {
    int s = i >> 4, d = (i & 15) << 3;
    half8 v = {};
    if (s < SEQ_KV) v = *(const half8*)(kv + kvbase + (size_t)s*2048 + d);
    *(half8*)(K_lds + s*136 + d) = v;
  }
  // stage V transposed: Vt[d][s], s padded to 96
  for (int i = tid; i < 96*16; i += 256) {
    int s = i >> 4, d = (i & 15) << 3;
    half8 v = {};
    if (s < SEQ_KV) v = *(const half8*)(kv + kvbase + (size_t)s*2048 + 1024 + d);
#pragma unroll
    for (int j = 0; j < 8; ++j) Vt_lds[(size_t)(d + j)*104 + s] = v[j];
  }
  // zero P pad cols [80,96) for all 64 rows
  {
    int rr = tid >> 2, cc = 80 + (tid & 3)*4;
    *reinterpret_cast<uint2*>(P_lds + (size_t)rr*104 + cc) = make_uint2(0u, 0u);
  }
  __syncthreads();

  // Q fragments (row = l4 within wave tile)
  const int qrow0 = blockIdx.x*64 + w*16;
  const half_t* qbase = q + ((size_t)b*SEQ_Q + qrow0 + l4)*D_EMBED + h*D_HEAD + lh*8;
  half8 qf[4];
#pragma unroll
  for (int kk = 0; kk < 4; ++kk) qf[kk] = *(const half8*)(qbase + kk*32);

  // S = Q K^T : 5 col-blocks of 16 kv, K-dim = 128 (4 steps)
  f32x4 sa[5] = {};
#pragma unroll
  for (int nb = 0; nb < 5; ++nb)
#pragma unroll
    for (int kk = 0; kk < 4; ++kk) {
      half8 kf = *(const half8*)(K_lds + (size_t)(nb*16 + l4)*136 + kk*32 + lh*8);
      sa[nb] = __builtin_amdgcn_mfma_f32_16x16x32_f16(qf[kk], kf, sa[nb], 0, 0, 0);
    }

  // softmax per q row (row = lh*4+j, cols spread over l4 across 16 lanes)
  const float scale = 0.08838834764831845f;  // 1/sqrt(128)
#pragma unroll
  for (int j = 0; j < 4; ++j) {
    float pv[5];
    float mx = -1e30f;
#pragma unroll
    for (int nb = 0; nb < 5; ++nb) {
      int col = nb*16 + l4;
      float sv = (col < SEQ_KV) ? sa[nb][j]*scale : -1e30f;
      pv[nb] = sv;
      mx = fmaxf(mx, sv);
    }
    mx = fmaxf(mx, __shfl_xor(mx, 1));
    mx = fmaxf(mx, __shfl_xor(mx, 2));
    mx = fmaxf(mx, __shfl_xor(mx, 4));
    mx = fmaxf(mx, __shfl_xor(mx, 8));
    float sm = 0.f;
#pragma unroll
    for (int nb = 0; nb < 5; ++nb) { float e = __expf(pv[nb] - mx); pv[nb] = e; sm += e; }
    sm += __shfl_xor(sm, 1);
    sm += __shfl_xor(sm, 2);
    sm += __shfl_xor(sm, 4);
    sm += __shfl_xor(sm, 8);
    const float inv = 1.f / sm;
    const int prow = w*16 + lh*4 + j;
#pragma unroll
    for (int nb = 0; nb < 5; ++nb)
      P_lds[(size_t)prow*104 + nb*16 + l4] = (half_t)(pv[nb]*inv);
  }
  // per-wave P region: same-wave ds ordering handled by compiler waitcnts

  // O = P V : A = P[16 x 96], B = V[96 x 128] read via Vt
  half8 pf[3];
#pragma unroll
  for (int kk = 0; kk < 3; ++kk)
    pf[kk] = *(const half8*)(P_lds + (size_t)(w*16 + l4)*104 + kk*32 + lh*8);
  f32x4 oa[8] = {};
#pragma unroll
  for (int nd = 0; nd < 8; ++nd)
#pragma unroll
    for (int kk = 0; kk < 3; ++kk) {
      half8 vf = *(const half8*)(Vt_lds + (size_t)(nd*16 + l4)*104 + kk*32 + lh*8);
      oa[nd] = __builtin_amdgcn_mfma_f32_16x16x32_f16(pf[kk], vf, oa[nd], 0, 0, 0);
    }
  // write in place over q (wave writes exactly the rows/cols it read)
#pragma unroll
  for (int nd = 0; nd < 8; ++nd) {
#pragma unroll
    for (int j = 0; j < 4; ++j) {
      const size_t row = (size_t)b*SEQ_Q + qrow0 + lh*4 + j;
      q[row*D_EMBED + h*D_HEAD + nd*16 + l4] = (half_t)oa[nd][j];
    }
  }
}

// ---------------- launch ----------------
extern "C" void kernel_launch(void* const* d_in, const int* in_sizes, int n_in,
                              void* d_out, int out_size, void* d_ws, size_t ws_size,
                              hipStream_t stream) {
  (void)in_sizes; (void)n_in; (void)out_size; (void)ws_size;
  const float* x  = (const float*)d_in[0];
  const float* y  = (const float*)d_in[1];
  const float* Wq = (const float*)d_in[2];
  const float* bq = (const float*)d_in[3];
  const float* Wk = (const float*)d_in[4];
  const float* bk = (const float*)d_in[5];
  const float* Wv = (const float*)d_in[6];
  const float* bv = (const float*)d_in[7];
  const float* Wo = (const float*)d_in[8];
  const float* bo = (const float*)d_in[9];

  char* ws = (char*)d_ws;
  half_t* q    = (half_t*)(ws + WS_Q);
  half_t* Wqt  = (half_t*)(ws + WS_WQT);
  half_t* Wot  = (half_t*)(ws + WS_WOT);
  half_t* Wkvt = (half_t*)(ws + WS_WKVT);
  half_t* yh   = (half_t*)(ws + WS_YH);
  half_t* kvb  = (half_t*)(ws + WS_KV);
  float*  bkv  = (float*)(ws + WS_BKV);

  dim3 tb(32, 8);
  // weights -> [N][K] fp16
  transpose_f32f16<<<dim3(32, 32), tb, 0, stream>>>(Wq, Wqt, 1024, 1024);
  transpose_f32f16<<<dim3(32, 24), tb, 0, stream>>>(Wk, Wkvt, 768, 1024);
  transpose_f32f16<<<dim3(32, 24), tb, 0, stream>>>(Wv, Wkvt + (size_t)1024*768, 768, 1024);
  transpose_f32f16<<<dim3(32, 32), tb, 0, stream>>>(Wo, Wot, 1024, 1024);
  convert_pad_y<<<ROWS_KV_PAD*D_CROSS/256, 256, 0, stream>>>(y, yh);
  concat_bias<<<2*D_EMBED/256, 256, 0, stream>>>(bk, bv, bkv);

  // K/V projection (fused): [640,768] @ [768,2048]
  gemm_f16<false, false><<<dim3(16, 5), 256, 0, stream>>>(yh, Wkvt, bkv, kvb, ROWS_KV_PAD, 2048, 768);
  // Q projection: fp32 A reg-staged: [32768,1024] @ [1024,1024] -> q fp16
  gemm_f16<true, false><<<dim3(8, 256), 256, 0, stream>>>(x, Wqt, bq, q, M_Q, 1024, 1024);
  // attention (in-place over q)
  attn_kernel<<<dim3(64, 64), 256, 0, stream>>>(q, kvb);
  // O projection: [32768,1024] @ [1024,1024] -> fp32 d_out
  gemm_f16<false, true><<<dim3(8, 256), 256, 0, stream>>>(q, Wot, bo, (float*)d_out, M_Q, 1024, 1024);
}

// Round 2
// 339.896 us; speedup vs baseline: 1.1215x; 1.1215x over previous
//
#include <hip/hip_runtime.h>

typedef _Float16 half_t;
typedef _Float16 half8 __attribute__((ext_vector_type(8)));
typedef float f32x4 __attribute__((ext_vector_type(4)));

#define D_EMBED   1024
#define D_CROSS   768
#define N_HEADS   8
#define D_HEAD    128
#define BATCH     8
#define SEQ_Q     4096
#define SEQ_KV    77
#define M_Q       (BATCH*SEQ_Q)     /* 32768 */
#define ROWS_KV   (BATCH*SEQ_KV)    /* 616   */
#define ROWS_KV_PAD 640

// ---------------- workspace layout (bytes, all 256-aligned) ----------------
#define WS_Q     ((size_t)0)                                  // q, later attn-out in place: 32768*1024*2
#define WS_WQT   (WS_Q    + (size_t)M_Q*D_EMBED*2)            // Wq^T fp16 [1024][1024]
#define WS_WOT   (WS_WQT  + (size_t)D_EMBED*D_EMBED*2)        // Wo^T fp16 [1024][1024]
#define WS_WKVT  (WS_WOT  + (size_t)D_EMBED*D_EMBED*2)        // [Wk;Wv]^T fp16 [2048][768]
#define WS_YH    (WS_WKVT + (size_t)2*D_EMBED*D_CROSS*2)      // y fp16 padded [640][768]
#define WS_KV    (WS_YH   + (size_t)ROWS_KV_PAD*D_CROSS*2)    // kv fp16 [640][2048]
#define WS_BKV   (WS_KV   + (size_t)ROWS_KV_PAD*2*D_EMBED*2)  // bias concat fp32 [2048]

__device__ __forceinline__ void gload_lds16(const void* g, void* lds) {
  __builtin_amdgcn_global_load_lds(
      (const __attribute__((address_space(1))) unsigned int*)g,
      (__attribute__((address_space(3))) unsigned int*)lds, 16, 0, 0);
}

// ---------------- prep kernels ----------------
// dst[n][k] = (half) src[k][n];   src is [K][N] fp32, dst is [N][K] fp16
__global__ void transpose_f32f16(const float* __restrict__ src, half_t* __restrict__ dst,
                                 int K, int N) {
  __shared__ float tile[32][33];
  int n0 = blockIdx.x * 32, k0 = blockIdx.y * 32;
  int tx = threadIdx.x, ty = threadIdx.y;
#pragma unroll
  for (int j = 0; j < 4; ++j)
    tile[ty + j*8][tx] = src[(size_t)(k0 + ty + j*8)*N + n0 + tx];
  __syncthreads();
#pragma unroll
  for (int j = 0; j < 4; ++j)
    dst[(size_t)(n0 + ty + j*8)*K + k0 + tx] = (half_t)tile[tx][ty + j*8];
}

__global__ void convert_pad_y(const float* __restrict__ y, half_t* __restrict__ yh) {
  int idx = blockIdx.x * 256 + threadIdx.x;         // grid covers 640*768 exactly
  int s = idx / D_CROSS;
  yh[idx] = (s < ROWS_KV) ? (half_t)y[idx] : (half_t)0.f;
}

__global__ void concat_bias(const float* __restrict__ bk, const float* __restrict__ bv,
                            float* __restrict__ bkv) {
  int i = blockIdx.x * 256 + threadIdx.x;           // grid = 2048 threads
  bkv[i] = (i < D_EMBED) ? bk[i] : bv[i - D_EMBED];
}

// ---------------- GEMM: C[M,N] = A[M,K] * Bt[N,K]^T + bias[N] ----------------
// 128x128 tile, BK=32, 256 threads (4 waves), wave tile 64x64 = 4x4 frags of 16x16x32_f16.
// AF32: A is fp32 in global, reg-stage + convert to fp16 LDS. Else fp16 via global_load_lds.
// SWZ (requires gridDim.x == 8): remap so all 8 N-blocks of an M-panel land on the
// SAME XCD in consecutive dispatch slots -> A panel read from HBM once, then L2-hit.
template<bool AF32, bool OUTF32, bool SWZ>
__global__ __launch_bounds__(256, 2)
void gemm_f16(const void* __restrict__ Av, const half_t* __restrict__ Bt,
              const float* __restrict__ bias, void* __restrict__ Cv,
              int M, int N, int K) {
  __shared__ half_t As[128*32];
  __shared__ half_t Bs[128*32];
  const int tid = threadIdx.x;
  const int l  = tid & 63;
  const int w  = tid >> 6;
  const int l4 = l & 15, lh = l >> 4;

  int bx, by;
  if constexpr (SWZ) {
    // dispatch slot s -> (bx,by); slots s with equal s%8 share an XCD (round-robin),
    // and the 8 column-blocks of panel `by` occupy 8 consecutive such slots.
    const int s = blockIdx.x + (blockIdx.y << 3);
    bx = (s >> 3) & 7;
    by = (s & 7) + ((s >> 6) << 3);
  } else {
    bx = blockIdx.x; by = blockIdx.y;
  }
  const int bn0 = bx * 128;
  const int bm0 = by * 128;
  const int wr = w >> 1, wc = w & 1;

  f32x4 acc[4][4] = {};
  const int nk = K >> 5;

  for (int kt = 0; kt < nk; ++kt) {
    // ---- stage B (always fp16, global_load_lds 16B) : Bs[row_n][k] ----
    {
      const half_t* g0 = Bt + (size_t)(bn0 + w*16 + (l >> 2))*K + kt*32 + (l & 3)*8;
      gload_lds16(g0, (char*)Bs + w*1024);
      const half_t* g1 = Bt + (size_t)(bn0 + 64 + w*16 + (l >> 2))*K + kt*32 + (l & 3)*8;
      gload_lds16(g1, (char*)Bs + 4096 + w*1024);
    }
    // ---- stage A ----
    if constexpr (!AF32) {
      const half_t* A = (const half_t*)Av;
      const half_t* g0 = A + (size_t)(bm0 + w*16 + (l >> 2))*K + kt*32 + (l & 3)*8;
      gload_lds16(g0, (char*)As + w*1024);
      const half_t* g1 = A + (size_t)(bm0 + 64 + w*16 + (l >> 2))*K + kt*32 + (l & 3)*8;
      gload_lds16(g1, (char*)As + 4096 + w*1024);
    } else {
      const float* A = (const float*)Av;
      const int row = tid >> 2;            // 0..63
      const int c0  = (tid & 3) * 8;       // half-elem col
#pragma unroll
      for (int r = 0; r < 2; ++r) {
        const float* g = A + (size_t)(bm0 + r*64 + row)*K + kt*32 + c0;
        f32x4 f0 = *(const f32x4*)g;
        f32x4 f1 = *(const f32x4*)(g + 4);
        half8 hv;
        hv[0]=(half_t)f0[0]; hv[1]=(half_t)f0[1]; hv[2]=(half_t)f0[2]; hv[3]=(half_t)f0[3];
        hv[4]=(half_t)f1[0]; hv[5]=(half_t)f1[1]; hv[6]=(half_t)f1[2]; hv[7]=(half_t)f1[3];
        *(half8*)(As + (size_t)(r*64 + row)*32 + c0) = hv;
      }
    }
    __syncthreads();
    // ---- compute ----
    half8 af[4], bf[4];
#pragma unroll
    for (int m = 0; m < 4; ++m)
      af[m] = *(const half8*)(As + (size_t)(wr*64 + m*16 + l4)*32 + lh*8);
#pragma unroll
    for (int n = 0; n < 4; ++n)
      bf[n] = *(const half8*)(Bs + (size_t)(wc*64 + n*16 + l4)*32 + lh*8);
#pragma unroll
    for (int m = 0; m < 4; ++m)
#pragma unroll
      for (int n = 0; n < 4; ++n)
        acc[m][n] = __builtin_amdgcn_mfma_f32_16x16x32_f16(af[m], bf[n], acc[m][n], 0, 0, 0);
    __syncthreads();
  }

  // ---- epilogue: C row = bm0+wr*64+m*16+lh*4+j, col = bn0+wc*64+n*16+l4 ----
  const int c_base = bn0 + wc*64;
  const int r_base = bm0 + wr*64;
#pragma unroll
  for (int n = 0; n < 4; ++n) {
    const int col = c_base + n*16 + l4;
    const float bvv = bias[col];
#pragma unroll
    for (int m = 0; m < 4; ++m) {
#pragma unroll
      for (int j = 0; j < 4; ++j) {
        const int row = r_base + m*16 + lh*4 + j;
        const float v = acc[m][n][j] + bvv;
        if constexpr (OUTF32) ((float*)Cv)[(size_t)row*N + col] = v;
        else                  ((half_t*)Cv)[(size_t)row*N + col] = (half_t)v;
      }
    }
  }
}

// ---------------- attention ----------------
// grid (64 q-tiles, 64 bh). Block = 4 waves, each wave = 16 q rows.
// q: [32768][1024] fp16 (in-place output). kv: [640][2048] fp16, k cols 0..1023, v cols 1024..2047.
__global__ __launch_bounds__(256, 2)
void attn_kernel(half_t* __restrict__ q, const half_t* __restrict__ kv) {
  __shared__ half_t K_lds[80*136];     // [kv_row][d], stride 136 halfs (272B, 16B-mult)
  __shared__ half_t Vt_lds[128*104];   // [d][kv_row], stride 104 halfs (208B, 16B-mult)
  __shared__ half_t P_lds[64*104];     // [q_row 0..63][kv 0..95 + pad]
  const int tid = threadIdx.x;
  const int l = tid & 63, w = tid >> 6;
  const int l4 = l & 15, lh = l >> 4;
  const int bh = blockIdx.y;
  const int b = bh >> 3, h = bh & 7;
  const size_t kvbase = (size_t)b*SEQ_KV*2048 + (size_t)h*D_HEAD;

  // stage K: 80 rows x 128 d (zero-pad rows >= 77)
  for (int i = tid; i < 80*16; i += 256) {
    int s = i >> 4, d = (i & 15) << 3;
    half8 v = {};
    if (s < SEQ_KV) v = *(const half8*)(kv + kvbase + (size_t)s*2048 + d);
    *(half8*)(K_lds + s*136 + d) = v;
  }
  // stage V transposed: Vt[d][s], s padded to 96
  for (int i = tid; i < 96*16; i += 256) {
    int s = i >> 4, d = (i & 15) << 3;
    half8 v = {};
    if (s < SEQ_KV) v = *(const half8*)(kv + kvbase + (size_t)s*2048 + 1024 + d);
#pragma unroll
    for (int j = 0; j < 8; ++j) Vt_lds[(size_t)(d + j)*104 + s] = v[j];
  }
  // zero P pad cols [80,96) for all 64 rows
  {
    int rr = tid >> 2, cc = 80 + (tid & 3)*4;
    *reinterpret_cast<uint2*>(P_lds + (size_t)rr*104 + cc) = make_uint2(0u, 0u);
  }
  __syncthreads();

  // Q fragments (row = l4 within wave tile)
  const int qrow0 = blockIdx.x*64 + w*16;
  const half_t* qbase = q + ((size_t)b*SEQ_Q + qrow0 + l4)*D_EMBED + h*D_HEAD + lh*8;
  half8 qf[4];
#pragma unroll
  for (int kk = 0; kk < 4; ++kk) qf[kk] = *(const half8*)(qbase + kk*32);

  // S = Q K^T : 5 col-blocks of 16 kv, K-dim = 128 (4 steps)
  f32x4 sa[5] = {};
#pragma unroll
  for (int nb = 0; nb < 5; ++nb)
#pragma unroll
    for (int kk = 0; kk < 4; ++kk) {
      half8 kf = *(const half8*)(K_lds + (size_t)(nb*16 + l4)*136 + kk*32 + lh*8);
      sa[nb] = __builtin_amdgcn_mfma_f32_16x16x32_f16(qf[kk], kf, sa[nb], 0, 0, 0);
    }

  // softmax per q row (row = lh*4+j, cols spread over l4 across 16 lanes)
  const float scale = 0.08838834764831845f;  // 1/sqrt(128)
#pragma unroll
  for (int j = 0; j < 4; ++j) {
    float pv[5];
    float mx = -1e30f;
#pragma unroll
    for (int nb = 0; nb < 5; ++nb) {
      int col = nb*16 + l4;
      float sv = (col < SEQ_KV) ? sa[nb][j]*scale : -1e30f;
      pv[nb] = sv;
      mx = fmaxf(mx, sv);
    }
    mx = fmaxf(mx, __shfl_xor(mx, 1));
    mx = fmaxf(mx, __shfl_xor(mx, 2));
    mx = fmaxf(mx, __shfl_xor(mx, 4));
    mx = fmaxf(mx, __shfl_xor(mx, 8));
    float sm = 0.f;
#pragma unroll
    for (int nb = 0; nb < 5; ++nb) { float e = __expf(pv[nb] - mx); pv[nb] = e; sm += e; }
    sm += __shfl_xor(sm, 1);
    sm += __shfl_xor(sm, 2);
    sm += __shfl_xor(sm, 4);
    sm += __shfl_xor(sm, 8);
    const float inv = 1.f / sm;
    const int prow = w*16 + lh*4 + j;
#pragma unroll
    for (int nb = 0; nb < 5; ++nb)
      P_lds[(size_t)prow*104 + nb*16 + l4] = (half_t)(pv[nb]*inv);
  }
  // per-wave P region: same-wave ds ordering handled by compiler waitcnts

  // O = P V : A = P[16 x 96], B = V[96 x 128] read via Vt
  half8 pf[3];
#pragma unroll
  for (int kk = 0; kk < 3; ++kk)
    pf[kk] = *(const half8*)(P_lds + (size_t)(w*16 + l4)*104 + kk*32 + lh*8);
  f32x4 oa[8] = {};
#pragma unroll
  for (int nd = 0; nd < 8; ++nd)
#pragma unroll
    for (int kk = 0; kk < 3; ++kk) {
      half8 vf = *(const half8*)(Vt_lds + (size_t)(nd*16 + l4)*104 + kk*32 + lh*8);
      oa[nd] = __builtin_amdgcn_mfma_f32_16x16x32_f16(pf[kk], vf, oa[nd], 0, 0, 0);
    }
  // write in place over q (wave writes exactly the rows/cols it read)
#pragma unroll
  for (int nd = 0; nd < 8; ++nd) {
#pragma unroll
    for (int j = 0; j < 4; ++j) {
      const size_t row = (size_t)b*SEQ_Q + qrow0 + lh*4 + j;
      q[row*D_EMBED + h*D_HEAD + nd*16 + l4] = (half_t)oa[nd][j];
    }
  }
}

// ---------------- launch ----------------
extern "C" void kernel_launch(void* const* d_in, const int* in_sizes, int n_in,
                              void* d_out, int out_size, void* d_ws, size_t ws_size,
                              hipStream_t stream) {
  (void)in_sizes; (void)n_in; (void)out_size; (void)ws_size;
  const float* x  = (const float*)d_in[0];
  const float* y  = (const float*)d_in[1];
  const float* Wq = (const float*)d_in[2];
  const float* bq = (const float*)d_in[3];
  const float* Wk = (const float*)d_in[4];
  const float* bk = (const float*)d_in[5];
  const float* Wv = (const float*)d_in[6];
  const float* bv = (const float*)d_in[7];
  const float* Wo = (const float*)d_in[8];
  const float* bo = (const float*)d_in[9];

  char* ws = (char*)d_ws;
  half_t* q    = (half_t*)(ws + WS_Q);
  half_t* Wqt  = (half_t*)(ws + WS_WQT);
  half_t* Wot  = (half_t*)(ws + WS_WOT);
  half_t* Wkvt = (half_t*)(ws + WS_WKVT);
  half_t* yh   = (half_t*)(ws + WS_YH);
  half_t* kvb  = (half_t*)(ws + WS_KV);
  float*  bkv  = (float*)(ws + WS_BKV);

  dim3 tb(32, 8);
  // weights -> [N][K] fp16
  transpose_f32f16<<<dim3(32, 32), tb, 0, stream>>>(Wq, Wqt, 1024, 1024);
  transpose_f32f16<<<dim3(32, 24), tb, 0, stream>>>(Wk, Wkvt, 768, 1024);
  transpose_f32f16<<<dim3(32, 24), tb, 0, stream>>>(Wv, Wkvt + (size_t)1024*768, 768, 1024);
  transpose_f32f16<<<dim3(32, 32), tb, 0, stream>>>(Wo, Wot, 1024, 1024);
  convert_pad_y<<<ROWS_KV_PAD*D_CROSS/256, 256, 0, stream>>>(y, yh);
  concat_bias<<<2*D_EMBED/256, 256, 0, stream>>>(bk, bv, bkv);

  // K/V projection (fused): [640,768] @ [768,2048]
  gemm_f16<false, false, false><<<dim3(16, 5), 256, 0, stream>>>(yh, Wkvt, bkv, kvb, ROWS_KV_PAD, 2048, 768);
  // Q projection: fp32 A reg-staged, XCD panel-coherent swizzle
  gemm_f16<true, false, true><<<dim3(8, 256), 256, 0, stream>>>(x, Wqt, bq, q, M_Q, 1024, 1024);
  // attention (in-place over q)
  attn_kernel<<<dim3(64, 64), 256, 0, stream>>>(q, kvb);
  // O projection: XCD panel-coherent swizzle
  gemm_f16<false, true, true><<<dim3(8, 256), 256, 0, stream>>>(q, Wot, bo, (float*)d_out, M_Q, 1024, 1024);
}